// Round 1
// baseline (439.458 us; speedup 1.0000x reference)
//
#include <hip/hip_runtime.h>
#include <math.h>

typedef short short8 __attribute__((ext_vector_type(8)));
typedef float fx4 __attribute__((ext_vector_type(4)));
typedef unsigned short ushort;
typedef unsigned int uint;
typedef uint uint2v __attribute__((ext_vector_type(2)));

#define MFMA16(a, b, c) __builtin_amdgcn_mfma_f32_16x16x32_bf16(a, b, c, 0, 0, 0)

// ---- constants ----
// segments: len {2048,2048,4096}, dil {1,2,4}; q rows packed at [0,2048,4096];
// k/v rows (dilated) packed at [0,2048,3072], total 4096.
#define S_TOT 8192
#define NH 16
#define HD 64

__device__ __forceinline__ ushort f2bf(float f) {
    union { float f; uint u; } v; v.f = f;
    uint r = v.u + 0x7fffu + ((v.u >> 16) & 1u);
    return (ushort)(r >> 16);
}

__device__ __forceinline__ void gl_lds16(const void* g, void* l) {
    __builtin_amdgcn_global_load_lds(
        (const __attribute__((address_space(1))) void*)g,
        (__attribute__((address_space(3))) void*)l, 16, 0, 0);
}

// ---- scratch (static device globals: independent of ws_size; fully
// rewritten every call before any read, so poison-safe & deterministic) ----
__device__ ushort g_XB[8192 * 1024];      // x bf16 [s][k]
__device__ ushort g_WQB[3072 * 1024];     // Wqkv bf16 [n][k]
__device__ ushort g_WOB[1024 * 1024];     // Wout bf16 [n][k]
__device__ ushort g_QSEG[16 * 8192 * 64]; // [h][qrow][d], permuted, pre-scaled by 1/8
__device__ ushort g_KSEG[16 * 4096 * 64]; // [h][krow][d], permuted+dilated
__device__ ushort g_VSEG[16 * 4096 * 64]; // [h][krow][d]
__device__ ushort g_VT[16 * 64 * 4096];   // [h][d][krow]  (V transposed)
__device__ ushort g_ATTN[8192 * 1024];    // [qrow][h*64+d] bf16 (permuted row space)
__device__ int g_QROW[8192];              // s -> permuted q row (global)
__device__ int g_KVROW[8192];             // s -> dilated k/v row (global) or -1

// ---------------- convert f32 -> bf16 ----------------
__global__ __launch_bounds__(256) void cvt_kernel(const float* __restrict__ x,
                                                  const float* __restrict__ wq,
                                                  const float* __restrict__ wo) {
    int idx = blockIdx.x * 256 + threadIdx.x;
    const int NX = 8192 * 1024 / 4, NQ = 3072 * 1024 / 4, NO = 1024 * 1024 / 4;
    const float* s; ushort* d; int rel;
    if (idx < NX)            { s = x;  d = g_XB;  rel = idx; }
    else if (idx < NX + NQ)  { s = wq; d = g_WQB; rel = idx - NX; }
    else if (idx < NX + NQ + NO) { s = wo; d = g_WOB; rel = idx - NX - NQ; }
    else return;
    fx4 v = *(const fx4*)(s + (long)rel * 4);
    uint lo = f2bf(v[0]) | ((uint)f2bf(v[1]) << 16);
    uint hi = f2bf(v[2]) | ((uint)f2bf(v[3]) << 16);
    uint2v w; w[0] = lo; w[1] = hi;
    *(uint2v*)(d + (long)rel * 4) = w;
}

// ---------------- Hilbert perms + scatter metadata ----------------
__global__ __launch_bounds__(1024) void perm_kernel() {
    __shared__ int perm_lds[4096];
    __shared__ int inv_lds[4096];
    __shared__ int sc[1024];
    int seg = blockIdx.x;
    int L     = (seg == 2) ? 4096 : 2048;
    int dil   = (seg == 0) ? 1 : (seg == 1) ? 2 : 4;
    int pos   = (seg == 0) ? 0 : (seg == 1) ? 2048 : 4096;
    int kbase = (seg == 0) ? 0 : (seg == 1) ? 2048 : 3072;
    int tid = threadIdx.x;

    int lin[4]; int flg[4]; int cnt = 0;
    #pragma unroll
    for (int c = 0; c < 4; c++) {
        int d = tid * 4 + c;
        int x = 0, y = 0, t = d;
        for (int s = 1; s < 64; s <<= 1) {
            int rx = (t >> 1) & 1;
            int ry = (t ^ rx) & 1;
            if (ry == 0) {
                if (rx == 1) { x = s - 1 - x; y = s - 1 - y; }
                int tmp = x; x = y; y = tmp;
            }
            x += s * rx; y += s * ry; t >>= 2;
        }
        lin[c] = y * 64 + x;
        flg[c] = (lin[c] < L) ? 1 : 0;
        cnt += flg[c];
    }
    sc[tid] = cnt; __syncthreads();
    for (int off = 1; off < 1024; off <<= 1) {
        int v = sc[tid];
        int a = (tid >= off) ? sc[tid - off] : 0;
        __syncthreads();
        sc[tid] = v + a;
        __syncthreads();
    }
    int base = sc[tid] - cnt;
    #pragma unroll
    for (int c = 0; c < 4; c++) if (flg[c]) perm_lds[base++] = lin[c];
    __syncthreads();
    for (int i = tid; i < L; i += 1024) inv_lds[perm_lds[i]] = i;
    __syncthreads();
    for (int p = tid; p < L; p += 1024) {
        int i = inv_lds[p];
        int s = pos + p;
        g_QROW[s] = pos + i;
        g_KVROW[s] = ((i & (dil - 1)) == 0) ? (kbase + i / dil) : -1;
    }
}

// ---------------- QKV GEMM: out[s][n] = x@Wqkv^T + b, scatter epilogue ----------------
__global__ __launch_bounds__(256) void qkv_gemm(const float* __restrict__ bias) {
    __shared__ __align__(16) ushort As[128 * 32];
    __shared__ __align__(16) ushort Bs[128 * 32];
    int tid = threadIdx.x;
    int lane = tid & 63, wid = tid >> 6;
    int lq = lane & 15, lg = lane >> 4;
    int row0 = blockIdx.x * 128, col0 = blockIdx.y * 128;
    int wm = (wid >> 1) * 64, wn = (wid & 1) * 64;
    fx4 acc[4][4] = {};
    for (int kt = 0; kt < 32; kt++) {
        {
            const ushort* ga = g_XB + (long)row0 * 1024 + kt * 32;
            const ushort* gb = g_WQB + (long)col0 * 1024 + kt * 32;
            int c0 = tid, c1 = tid + 256;
            gl_lds16(ga + (c0 >> 2) * 1024 + (c0 & 3) * 8, As + c0 * 8);
            gl_lds16(ga + (c1 >> 2) * 1024 + (c1 & 3) * 8, As + c1 * 8);
            gl_lds16(gb + (c0 >> 2) * 1024 + (c0 & 3) * 8, Bs + c0 * 8);
            gl_lds16(gb + (c1 >> 2) * 1024 + (c1 & 3) * 8, Bs + c1 * 8);
        }
        asm volatile("s_waitcnt vmcnt(0)" ::: "memory");
        __syncthreads();
        short8 af[4], bfr[4];
        #pragma unroll
        for (int mi = 0; mi < 4; mi++)
            af[mi] = *(const short8*)(As + (wm + mi * 16 + lq) * 32 + lg * 8);
        #pragma unroll
        for (int ni = 0; ni < 4; ni++)
            bfr[ni] = *(const short8*)(Bs + (wn + ni * 16 + lq) * 32 + lg * 8);
        #pragma unroll
        for (int mi = 0; mi < 4; mi++)
            #pragma unroll
            for (int ni = 0; ni < 4; ni++)
                acc[mi][ni] = MFMA16(af[mi], bfr[ni], acc[mi][ni]);
        __syncthreads();
    }
    int comp = col0 >> 10;  // uniform per block (128 | 1024)
    #pragma unroll
    for (int mi = 0; mi < 4; mi++) {
        int mbase = row0 + wm + mi * 16 + lg * 4;
        #pragma unroll
        for (int r = 0; r < 4; r++) {
            int m = mbase + r;
            int qr = g_QROW[m];
            int kr = g_KVROW[m];
            #pragma unroll
            for (int ni = 0; ni < 4; ni++) {
                int n = col0 + wn + ni * 16 + lq;
                float val = acc[mi][ni][r] + bias[n];
                int h = (n >> 6) & 15, dd = n & 63;
                if (comp == 0) {
                    g_QSEG[((long)h * 8192 + qr) * 64 + dd] = f2bf(val * 0.125f);
                } else if (kr >= 0) {
                    if (comp == 1) g_KSEG[((long)h * 4096 + kr) * 64 + dd] = f2bf(val);
                    else           g_VSEG[((long)h * 4096 + kr) * 64 + dd] = f2bf(val);
                }
            }
        }
    }
}

// ---------------- V transpose: [h][row][d] -> [h][d][row] ----------------
__global__ __launch_bounds__(256) void vtrans_kernel() {
    __shared__ __align__(16) ushort tile[64 * 80];  // row stride 80 (160B, 16B-aligned)
    int b = blockIdx.x; int h = b >> 6; int rt = b & 63;
    const ushort* src = g_VSEG + ((long)h * 4096 + rt * 64) * 64;
    int tid = threadIdx.x;
    for (int c = tid; c < 512; c += 256) {
        int row = c >> 3, ch = c & 7;
        *(short8*)&tile[row * 80 + ch * 8] = *(const short8*)(src + row * 64 + ch * 8);
    }
    __syncthreads();
    for (int c = tid; c < 512; c += 256) {
        int d = c >> 3, oc = c & 7;
        ushort tmp[8];
        #pragma unroll
        for (int e = 0; e < 8; e++) tmp[e] = tile[(oc * 8 + e) * 80 + d];
        *(short8*)&g_VT[((long)h * 64 + d) * 4096 + rt * 64 + oc * 8] = *(short8*)tmp;
    }
}

// ---------------- attention: flash, swapped QK^T, OUT^T = V^T P^T ----------------
__global__ __launch_bounds__(256) void attn_kernel() {
    __shared__ __align__(16) ushort Plds[4][16 * 72];  // per-wave P [q][key], stride 72
    int bid = blockIdx.x;
    int seg, rel;
    if (bid < 512)       { seg = 0; rel = bid; }
    else if (bid < 1024) { seg = 1; rel = bid - 512; }
    else                 { seg = 2; rel = bid - 1024; }
    int h, qt;
    if (seg < 2) { h = rel >> 5; qt = rel & 31; }
    else         { h = rel >> 6; qt = rel & 63; }
    int qbase = (seg == 0) ? 0 : (seg == 1) ? 2048 : 4096;
    int kbase = (seg == 0) ? 0 : (seg == 1) ? 2048 : 3072;
    int Lk    = (seg == 0) ? 2048 : 1024;
    int tid = threadIdx.x;
    int lane = tid & 63, wid = tid >> 6;
    int lq = lane & 15, lg = lane >> 4;
    int qrow0 = qbase + qt * 64 + wid * 16;

    const ushort* qp = g_QSEG + ((long)h * 8192 + qrow0) * 64;
    short8 qf0 = *(const short8*)(qp + lq * 64 + lg * 8);
    short8 qf1 = *(const short8*)(qp + lq * 64 + 32 + lg * 8);
    const ushort* kp = g_KSEG + (long)h * 4096 * 64;
    const ushort* vp = g_VT + (long)h * 64 * 4096;
    ushort* P = &Plds[wid][0];

    fx4 accT[4] = {};
    float m = -INFINITY, lsum = 0.f;
    int nkt = Lk >> 6;
    for (int kt = 0; kt < nkt; kt++) {
        int k0 = kbase + kt * 64;
        fx4 st[4];
        #pragma unroll
        for (int t = 0; t < 4; t++) {
            const ushort* kr = kp + (long)(k0 + t * 16 + lq) * 64 + lg * 8;
            short8 kf0 = *(const short8*)kr;
            short8 kf1 = *(const short8*)(kr + 32);
            fx4 s = {};
            s = MFMA16(kf0, qf0, s);   // S^T[key][q], q pre-scaled by 1/8
            s = MFMA16(kf1, qf1, s);
            st[t] = s;
        }
        float tmax = st[0][0];
        #pragma unroll
        for (int t = 0; t < 4; t++)
            #pragma unroll
            for (int r = 0; r < 4; r++) tmax = fmaxf(tmax, st[t][r]);
        tmax = fmaxf(tmax, __shfl_xor(tmax, 16));
        tmax = fmaxf(tmax, __shfl_xor(tmax, 32));
        float newm = fmaxf(m, tmax);
        float corr = __expf(m - newm);  // first iter: exp(-inf)=0
        m = newm;
        lsum *= corr;
        #pragma unroll
        for (int td = 0; td < 4; td++) {
            accT[td][0] *= corr; accT[td][1] *= corr;
            accT[td][2] *= corr; accT[td][3] *= corr;
        }
        #pragma unroll
        for (int t = 0; t < 4; t++) {
            float p0 = __expf(st[t][0] - newm);
            float p1 = __expf(st[t][1] - newm);
            float p2 = __expf(st[t][2] - newm);
            float p3 = __expf(st[t][3] - newm);
            lsum += (p0 + p1) + (p2 + p3);
            uint w0 = f2bf(p0) | ((uint)f2bf(p1) << 16);
            uint w1 = f2bf(p2) | ((uint)f2bf(p3) << 16);
            int key = t * 16 + lg * 4;
            *(uint*)(P + lq * 72 + key) = w0;
            *(uint*)(P + lq * 72 + key + 2) = w1;
        }
        short8 pb0 = *(const short8*)(P + lq * 72 + lg * 8);
        short8 pb1 = *(const short8*)(P + lq * 72 + 32 + lg * 8);
        #pragma unroll
        for (int td = 0; td < 4; td++) {
            const ushort* vr = vp + (long)(td * 16 + lq) * 4096 + k0 + lg * 8;
            short8 vf0 = *(const short8*)vr;
            short8 vf1 = *(const short8*)(vr + 32);
            accT[td] = MFMA16(vf0, pb0, accT[td]);  // OUT^T[d][q]
            accT[td] = MFMA16(vf1, pb1, accT[td]);
        }
    }
    lsum += __shfl_xor(lsum, 16);
    lsum += __shfl_xor(lsum, 32);
    float rinv = 1.0f / lsum;
    int orow = qrow0 + lq;
    ushort* op = g_ATTN + (long)orow * 1024 + h * 64;
    #pragma unroll
    for (int td = 0; td < 4; td++) {
        uint w0 = f2bf(accT[td][0] * rinv) | ((uint)f2bf(accT[td][1] * rinv) << 16);
        uint w1 = f2bf(accT[td][2] * rinv) | ((uint)f2bf(accT[td][3] * rinv) << 16);
        *(uint*)(op + td * 16 + lg * 4) = w0;
        *(uint*)(op + td * 16 + lg * 4 + 2) = w1;
    }
}

// ---------------- output GEMM: out[s][e] = attn[qrow[s]] @ Wout^T + b ----------------
__global__ __launch_bounds__(256) void out_gemm(const float* __restrict__ bias,
                                                float* __restrict__ out) {
    __shared__ __align__(16) ushort As[128 * 32];
    __shared__ __align__(16) ushort Bs[128 * 32];
    int tid = threadIdx.x;
    int lane = tid & 63, wid = tid >> 6;
    int lq = lane & 15, lg = lane >> 4;
    int row0 = blockIdx.x * 128, col0 = blockIdx.y * 128;
    int wm = (wid >> 1) * 64, wn = (wid & 1) * 64;
    int gr0 = g_QROW[row0 + (tid >> 2)];
    int gr1 = g_QROW[row0 + 64 + (tid >> 2)];
    fx4 acc[4][4] = {};
    for (int kt = 0; kt < 32; kt++) {
        {
            int kc = kt * 32 + (tid & 3) * 8;
            gl_lds16(g_ATTN + (long)gr0 * 1024 + kc, As + tid * 8);
            gl_lds16(g_ATTN + (long)gr1 * 1024 + kc, As + (tid + 256) * 8);
            const ushort* gb = g_WOB + (long)col0 * 1024 + kt * 32;
            int c0 = tid, c1 = tid + 256;
            gl_lds16(gb + (c0 >> 2) * 1024 + (c0 & 3) * 8, Bs + c0 * 8);
            gl_lds16(gb + (c1 >> 2) * 1024 + (c1 & 3) * 8, Bs + c1 * 8);
        }
        asm volatile("s_waitcnt vmcnt(0)" ::: "memory");
        __syncthreads();
        short8 af[4], bfr[4];
        #pragma unroll
        for (int mi = 0; mi < 4; mi++)
            af[mi] = *(const short8*)(As + (wm + mi * 16 + lq) * 32 + lg * 8);
        #pragma unroll
        for (int ni = 0; ni < 4; ni++)
            bfr[ni] = *(const short8*)(Bs + (wn + ni * 16 + lq) * 32 + lg * 8);
        #pragma unroll
        for (int mi = 0; mi < 4; mi++)
            #pragma unroll
            for (int ni = 0; ni < 4; ni++)
                acc[mi][ni] = MFMA16(af[mi], bfr[ni], acc[mi][ni]);
        __syncthreads();
    }
    #pragma unroll
    for (int mi = 0; mi < 4; mi++)
        #pragma unroll
        for (int r = 0; r < 4; r++) {
            int mm = row0 + wm + mi * 16 + lg * 4 + r;
            #pragma unroll
            for (int ni = 0; ni < 4; ni++) {
                int n = col0 + wn + ni * 16 + lq;
                out[(long)mm * 1024 + n] = acc[mi][ni][r] + bias[n];
            }
        }
}

extern "C" void kernel_launch(void* const* d_in, const int* in_sizes, int n_in,
                              void* d_out, int out_size, void* d_ws, size_t ws_size,
                              hipStream_t stream) {
    const float* x    = (const float*)d_in[0];
    const float* Wqkv = (const float*)d_in[1];
    const float* bqkv = (const float*)d_in[2];
    const float* Wout = (const float*)d_in[3];
    const float* bout = (const float*)d_in[4];
    float* out = (float*)d_out;
    (void)d_ws; (void)ws_size; (void)in_sizes; (void)n_in; (void)out_size;

    cvt_kernel<<<dim3(12288), dim3(256), 0, stream>>>(x, Wqkv, Wout);
    perm_kernel<<<dim3(3), dim3(1024), 0, stream>>>();
    qkv_gemm<<<dim3(64, 24), dim3(256), 0, stream>>>(bqkv);
    vtrans_kernel<<<dim3(1024), dim3(256), 0, stream>>>();
    attn_kernel<<<dim3(2048), dim3(256), 0, stream>>>();
    out_gemm<<<dim3(64, 8), dim3(256), 0, stream>>>(bout, out);
}

// Round 2
// 262.264 us; speedup vs baseline: 1.6756x; 1.6756x over previous
//
#include <hip/hip_runtime.h>
#include <math.h>

typedef short short8 __attribute__((ext_vector_type(8)));
typedef float fx4 __attribute__((ext_vector_type(4)));
typedef unsigned short ushort;
typedef unsigned int uint;
typedef uint uint2v __attribute__((ext_vector_type(2)));

#define MFMA16(a, b, c) __builtin_amdgcn_mfma_f32_16x16x32_bf16(a, b, c, 0, 0, 0)

// segments: len {2048,2048,4096}, dil {1,2,4}; q rows packed at [0,2048,4096];
// k/v rows (dilated) packed at [0,2048,3072], total 4096.

__device__ __forceinline__ ushort f2bf(float f) {
    union { float f; uint u; } v; v.f = f;
    uint r = v.u + 0x7fffu + ((v.u >> 16) & 1u);
    return (ushort)(r >> 16);
}

__device__ __forceinline__ void gl_lds16(const void* g, void* l) {
    __builtin_amdgcn_global_load_lds(
        (const __attribute__((address_space(1))) void*)g,
        (__attribute__((address_space(3))) void*)l, 16, 0, 0);
}

// ---- scratch (static device globals; fully rewritten every call) ----
__device__ ushort g_XB[8192 * 1024];      // x bf16 [s][k]
__device__ ushort g_WQB[3072 * 1024];     // Wqkv bf16 [n][k]
__device__ ushort g_WOB[1024 * 1024];     // Wout bf16 [n][k]
__device__ ushort g_QSEG[16 * 8192 * 64]; // [h][qrow][d], permuted, pre-scaled by 1/8
__device__ ushort g_KSEG[16 * 4096 * 64]; // [h][krow][d], permuted+dilated
__device__ ushort g_VSEG[16 * 4096 * 64]; // [h][krow][d]
__device__ ushort g_VT[16 * 64 * 4096];   // [h][d][krow]  (V transposed)
__device__ ushort g_ATTN[8192 * 1024];    // [qrow][h*64+d] bf16 (permuted row space)
__device__ int g_QROW[8192];              // s -> permuted q row (global)
__device__ int g_KVROW[8192];             // s -> dilated k/v row (global) or -1

// ---------------- convert f32 -> bf16 ----------------
__global__ __launch_bounds__(256) void cvt_kernel(const float* __restrict__ x,
                                                  const float* __restrict__ wq,
                                                  const float* __restrict__ wo) {
    int idx = blockIdx.x * 256 + threadIdx.x;
    const int NX = 8192 * 1024 / 4, NQ = 3072 * 1024 / 4, NO = 1024 * 1024 / 4;
    const float* s; ushort* d; int rel;
    if (idx < NX)            { s = x;  d = g_XB;  rel = idx; }
    else if (idx < NX + NQ)  { s = wq; d = g_WQB; rel = idx - NX; }
    else if (idx < NX + NQ + NO) { s = wo; d = g_WOB; rel = idx - NX - NQ; }
    else return;
    fx4 v = *(const fx4*)(s + (long)rel * 4);
    uint lo = f2bf(v[0]) | ((uint)f2bf(v[1]) << 16);
    uint hi = f2bf(v[2]) | ((uint)f2bf(v[3]) << 16);
    uint2v w; w[0] = lo; w[1] = hi;
    *(uint2v*)(d + (long)rel * 4) = w;
}

// ---------------- Hilbert perms + scatter metadata ----------------
__global__ __launch_bounds__(1024) void perm_kernel() {
    __shared__ int perm_lds[4096];
    __shared__ int inv_lds[4096];
    __shared__ int sc[1024];
    int seg = blockIdx.x;
    int L     = (seg == 2) ? 4096 : 2048;
    int dil   = (seg == 0) ? 1 : (seg == 1) ? 2 : 4;
    int pos   = (seg == 0) ? 0 : (seg == 1) ? 2048 : 4096;
    int kbase = (seg == 0) ? 0 : (seg == 1) ? 2048 : 3072;
    int tid = threadIdx.x;

    int lin[4]; int flg[4]; int cnt = 0;
    #pragma unroll
    for (int c = 0; c < 4; c++) {
        int d = tid * 4 + c;
        int x = 0, y = 0, t = d;
        for (int s = 1; s < 64; s <<= 1) {
            int rx = (t >> 1) & 1;
            int ry = (t ^ rx) & 1;
            if (ry == 0) {
                if (rx == 1) { x = s - 1 - x; y = s - 1 - y; }
                int tmp = x; x = y; y = tmp;
            }
            x += s * rx; y += s * ry; t >>= 2;
        }
        lin[c] = y * 64 + x;
        flg[c] = (lin[c] < L) ? 1 : 0;
        cnt += flg[c];
    }
    sc[tid] = cnt; __syncthreads();
    for (int off = 1; off < 1024; off <<= 1) {
        int v = sc[tid];
        int a = (tid >= off) ? sc[tid - off] : 0;
        __syncthreads();
        sc[tid] = v + a;
        __syncthreads();
    }
    int base = sc[tid] - cnt;
    #pragma unroll
    for (int c = 0; c < 4; c++) if (flg[c]) perm_lds[base++] = lin[c];
    __syncthreads();
    for (int i = tid; i < L; i += 1024) inv_lds[perm_lds[i]] = i;
    __syncthreads();
    for (int p = tid; p < L; p += 1024) {
        int i = inv_lds[p];
        int s = pos + p;
        g_QROW[s] = pos + i;
        g_KVROW[s] = ((i & (dil - 1)) == 0) ? (kbase + i / dil) : -1;
    }
}

// ---------------- QKV GEMM: out[s][n] = x@Wqkv^T + b, scatter epilogue ----------------
__global__ __launch_bounds__(256) void qkv_gemm(const float* __restrict__ bias) {
    __shared__ __align__(16) ushort As[128 * 32];
    __shared__ __align__(16) ushort Bs[128 * 32];
    int tid = threadIdx.x;
    int lane = tid & 63, wid = tid >> 6;
    int lq = lane & 15, lg = lane >> 4;
    int row0 = blockIdx.x * 128, col0 = blockIdx.y * 128;
    int wm = (wid >> 1) * 64, wn = (wid & 1) * 64;
    fx4 acc[4][4] = {};
    for (int kt = 0; kt < 32; kt++) {
        {
            const ushort* ga = g_XB + (long)row0 * 1024 + kt * 32;
            const ushort* gb = g_WQB + (long)col0 * 1024 + kt * 32;
            int c0 = tid, c1 = tid + 256;
            gl_lds16(ga + (c0 >> 2) * 1024 + (c0 & 3) * 8, As + c0 * 8);
            gl_lds16(ga + (c1 >> 2) * 1024 + (c1 & 3) * 8, As + c1 * 8);
            gl_lds16(gb + (c0 >> 2) * 1024 + (c0 & 3) * 8, Bs + c0 * 8);
            gl_lds16(gb + (c1 >> 2) * 1024 + (c1 & 3) * 8, Bs + c1 * 8);
        }
        asm volatile("s_waitcnt vmcnt(0)" ::: "memory");
        __syncthreads();
        short8 af[4], bfr[4];
        #pragma unroll
        for (int mi = 0; mi < 4; mi++)
            af[mi] = *(const short8*)(As + (wm + mi * 16 + lq) * 32 + lg * 8);
        #pragma unroll
        for (int ni = 0; ni < 4; ni++)
            bfr[ni] = *(const short8*)(Bs + (wn + ni * 16 + lq) * 32 + lg * 8);
        #pragma unroll
        for (int mi = 0; mi < 4; mi++)
            #pragma unroll
            for (int ni = 0; ni < 4; ni++)
                acc[mi][ni] = MFMA16(af[mi], bfr[ni], acc[mi][ni]);
        __syncthreads();
    }
    int comp = col0 >> 10;  // uniform per block (128 | 1024)
    #pragma unroll
    for (int mi = 0; mi < 4; mi++) {
        int mbase = row0 + wm + mi * 16 + lg * 4;
        #pragma unroll
        for (int r = 0; r < 4; r++) {
            int m = mbase + r;
            int qr = g_QROW[m];
            int kr = g_KVROW[m];
            #pragma unroll
            for (int ni = 0; ni < 4; ni++) {
                int n = col0 + wn + ni * 16 + lq;
                float val = acc[mi][ni][r] + bias[n];
                int h = (n >> 6) & 15, dd = n & 63;
                if (comp == 0) {
                    g_QSEG[((long)h * 8192 + qr) * 64 + dd] = f2bf(val * 0.125f);
                } else if (kr >= 0) {
                    if (comp == 1) g_KSEG[((long)h * 4096 + kr) * 64 + dd] = f2bf(val);
                    else           g_VSEG[((long)h * 4096 + kr) * 64 + dd] = f2bf(val);
                }
            }
        }
    }
}

// ---------------- V transpose: [h][row][d] -> [h][d][row] ----------------
__global__ __launch_bounds__(256) void vtrans_kernel() {
    __shared__ __align__(16) ushort tile[64 * 80];
    int b = blockIdx.x; int h = b >> 6; int rt = b & 63;
    const ushort* src = g_VSEG + ((long)h * 4096 + rt * 64) * 64;
    int tid = threadIdx.x;
    for (int c = tid; c < 512; c += 256) {
        int row = c >> 3, ch = c & 7;
        *(short8*)&tile[row * 80 + ch * 8] = *(const short8*)(src + row * 64 + ch * 8);
    }
    __syncthreads();
    for (int c = tid; c < 512; c += 256) {
        int d = c >> 3, oc = c & 7;
        ushort tmp[8];
        #pragma unroll
        for (int e = 0; e < 8; e++) tmp[e] = tile[(oc * 8 + e) * 80 + d];
        *(short8*)&g_VT[((long)h * 64 + d) * 4096 + rt * 64 + oc * 8] = *(short8*)tmp;
    }
}

// ---------------- attention: flash, LDS-staged K/VT (dbuf+swizzle), 32q/wave ----------------
// Block = 4 waves x 32 q-rows = 128 q rows. Grid: 16 heads x 64 q-blocks = 1024.
// K tile [64 key][64 d], VT tile [64 d][64 key] staged in LDS, XOR-swizzled
// (byte ^= (row&7)<<4) via inverse-swizzled global_load_lds source (rule #21).
__global__ __launch_bounds__(256, 3) void attn_kernel() {
    __shared__ __align__(16) ushort Kt[2][64 * 64];
    __shared__ __align__(16) ushort Vt[2][64 * 64];
    __shared__ __align__(16) ushort Plds[4][32 * 72];
    int bid = blockIdx.x;
    int h = bid >> 6, r = bid & 63;
    int seg  = (r < 16) ? 0 : (r < 32) ? 1 : 2;
    int qblk = r - ((seg == 0) ? 0 : (seg == 1) ? 16 : 32);
    int qbase = (seg == 0) ? 0 : (seg == 1) ? 2048 : 4096;
    int kbase = (seg == 0) ? 0 : (seg == 1) ? 2048 : 3072;
    int nkt   = (seg == 0) ? 32 : 16;

    int tid = threadIdx.x;
    int lane = tid & 63, wid = tid >> 6;
    int lq = lane & 15, lg = lane >> 4;
    int qrow0 = qbase + qblk * 128 + wid * 32;

    const ushort* kseg = g_KSEG + (long)h * 4096 * 64;
    const ushort* vtb0 = g_VT + (long)h * 64 * 4096 + kbase;
    ushort* P = &Plds[wid][0];

    // staging chunk geometry: chunk c of 512 -> row c>>3, 16B piece c&7;
    // source piece = (c&7) ^ (row&7)  (involution; read side applies same XOR)
    int c0 = tid, c1 = tid + 256;
    int r0 = c0 >> 3, e0 = (c0 & 7) ^ (r0 & 7);
    int r1 = c1 >> 3, e1 = (c1 & 7) ^ (r1 & 7);

#define STAGE(b, kt_) do {                                                   \
        const ushort* kg = kseg + (long)(kbase + (kt_) * 64) * 64;           \
        const ushort* vg = vtb0 + (kt_) * 64;                                \
        gl_lds16(kg + r0 * 64 + (e0 << 3), &Kt[b][c0 * 8]);                  \
        gl_lds16(kg + r1 * 64 + (e1 << 3), &Kt[b][c1 * 8]);                  \
        gl_lds16(vg + (long)r0 * 4096 + (e0 << 3), &Vt[b][c0 * 8]);          \
        gl_lds16(vg + (long)r1 * 4096 + (e1 << 3), &Vt[b][c1 * 8]);          \
    } while (0)

    // Q fragments (32 rows per wave, 2 q-subtiles), pre-scaled by 1/8
    const ushort* qp = g_QSEG + ((long)h * 8192 + qrow0) * 64;
    short8 qf[2][2];
    #pragma unroll
    for (int qt = 0; qt < 2; qt++)
        #pragma unroll
        for (int hf = 0; hf < 2; hf++)
            qf[qt][hf] = *(const short8*)(qp + (qt * 16 + lq) * 64 + hf * 32 + lg * 8);

    STAGE(0, 0);
    asm volatile("s_waitcnt vmcnt(0)" ::: "memory");
    __syncthreads();

    fx4 accT[4][2] = {};
    float m0 = -INFINITY, m1 = -INFINITY, l0 = 0.f, l1 = 0.f;
    int swz = (lq & 7);  // read-side XOR on the 16B-piece index

    for (int kt = 0; kt < nkt; kt++) {
        int cur = kt & 1;
        if (kt + 1 < nkt) STAGE(cur ^ 1, kt + 1);
        const ushort* Kc = Kt[cur];
        const ushort* Vc = Vt[cur];

        // ---- QK^T (swapped): S^T[key][q], 16 MFMA ----
        short8 kf[4][2];
        #pragma unroll
        for (int t = 0; t < 4; t++)
            #pragma unroll
            for (int hf = 0; hf < 2; hf++)
                kf[t][hf] = *(const short8*)(Kc + (t * 16 + lq) * 64 + (((hf * 4 + lg) ^ swz) << 3));
        fx4 st[4][2];
        #pragma unroll
        for (int t = 0; t < 4; t++)
            #pragma unroll
            for (int qt = 0; qt < 2; qt++) {
                fx4 s = {};
                s = MFMA16(kf[t][0], qf[qt][0], s);
                s = MFMA16(kf[t][1], qf[qt][1], s);
                st[t][qt] = s;
            }

        // ---- online softmax (deferred-max, THR=8) ----
        float t0 = st[0][0][0], t1 = st[0][1][0];
        #pragma unroll
        for (int t = 0; t < 4; t++)
            #pragma unroll
            for (int rr = 0; rr < 4; rr++) {
                t0 = fmaxf(t0, st[t][0][rr]);
                t1 = fmaxf(t1, st[t][1][rr]);
            }
        t0 = fmaxf(t0, __shfl_xor(t0, 16)); t0 = fmaxf(t0, __shfl_xor(t0, 32));
        t1 = fmaxf(t1, __shfl_xor(t1, 16)); t1 = fmaxf(t1, __shfl_xor(t1, 32));
        bool need = (t0 > m0 + 8.f) || (t1 > m1 + 8.f);
        if (__any(need)) {
            float nm0 = fmaxf(m0, t0), nm1 = fmaxf(m1, t1);
            float cr0 = __expf(m0 - nm0), cr1 = __expf(m1 - nm1);
            m0 = nm0; m1 = nm1;
            l0 *= cr0; l1 *= cr1;
            #pragma unroll
            for (int td = 0; td < 4; td++) {
                accT[td][0][0] *= cr0; accT[td][0][1] *= cr0;
                accT[td][0][2] *= cr0; accT[td][0][3] *= cr0;
                accT[td][1][0] *= cr1; accT[td][1][1] *= cr1;
                accT[td][1][2] *= cr1; accT[td][1][3] *= cr1;
            }
        }
        // P = exp(S - m), bf16, into per-wave LDS [32 q][72 key-stride]
        #pragma unroll
        for (int qt = 0; qt < 2; qt++) {
            float mm = qt ? m1 : m0;
            float ls = 0.f;
            #pragma unroll
            for (int t = 0; t < 4; t++) {
                float p0 = __expf(st[t][qt][0] - mm);
                float p1 = __expf(st[t][qt][1] - mm);
                float p2 = __expf(st[t][qt][2] - mm);
                float p3 = __expf(st[t][qt][3] - mm);
                ls += (p0 + p1) + (p2 + p3);
                uint2v w;
                w[0] = f2bf(p0) | ((uint)f2bf(p1) << 16);
                w[1] = f2bf(p2) | ((uint)f2bf(p3) << 16);
                *(uint2v*)(P + (qt * 16 + lq) * 72 + t * 16 + lg * 4) = w;
            }
            if (qt) l1 += ls; else l0 += ls;
        }

        // ---- PV: OUT^T += V^T * P^T, 16 MFMA ----
        short8 vf[4][2];
        #pragma unroll
        for (int td = 0; td < 4; td++)
            #pragma unroll
            for (int hf = 0; hf < 2; hf++)
                vf[td][hf] = *(const short8*)(Vc + (td * 16 + lq) * 64 + (((hf * 4 + lg) ^ swz) << 3));
        #pragma unroll
        for (int qt = 0; qt < 2; qt++) {
            short8 pb0 = *(const short8*)(P + (qt * 16 + lq) * 72 + lg * 8);
            short8 pb1 = *(const short8*)(P + (qt * 16 + lq) * 72 + 32 + lg * 8);
            #pragma unroll
            for (int td = 0; td < 4; td++) {
                accT[td][qt] = MFMA16(vf[td][0], pb0, accT[td][qt]);
                accT[td][qt] = MFMA16(vf[td][1], pb1, accT[td][qt]);
            }
        }

        asm volatile("s_waitcnt vmcnt(0)" ::: "memory");
        __syncthreads();
    }
#undef STAGE

    l0 += __shfl_xor(l0, 16); l0 += __shfl_xor(l0, 32);
    l1 += __shfl_xor(l1, 16); l1 += __shfl_xor(l1, 32);
    float ri0 = 1.0f / l0, ri1 = 1.0f / l1;
    #pragma unroll
    for (int qt = 0; qt < 2; qt++) {
        float ri = qt ? ri1 : ri0;
        ushort* op = g_ATTN + (long)(qrow0 + qt * 16 + lq) * 1024 + h * 64;
        #pragma unroll
        for (int td = 0; td < 4; td++) {
            uint2v w;
            w[0] = f2bf(accT[td][qt][0] * ri) | ((uint)f2bf(accT[td][qt][1] * ri) << 16);
            w[1] = f2bf(accT[td][qt][2] * ri) | ((uint)f2bf(accT[td][qt][3] * ri) << 16);
            *(uint2v*)(op + td * 16 + lg * 4) = w;
        }
    }
}

// ---------------- output GEMM: out[s][e] = attn[qrow[s]] @ Wout^T + b ----------------
__global__ __launch_bounds__(256) void out_gemm(const float* __restrict__ bias,
                                                float* __restrict__ out) {
    __shared__ __align__(16) ushort As[128 * 32];
    __shared__ __align__(16) ushort Bs[128 * 32];
    int tid = threadIdx.x;
    int lane = tid & 63, wid = tid >> 6;
    int lq = lane & 15, lg = lane >> 4;
    int row0 = blockIdx.x * 128, col0 = blockIdx.y * 128;
    int wm = (wid >> 1) * 64, wn = (wid & 1) * 64;
    int gr0 = g_QROW[row0 + (tid >> 2)];
    int gr1 = g_QROW[row0 + 64 + (tid >> 2)];
    fx4 acc[4][4] = {};
    for (int kt = 0; kt < 32; kt++) {
        {
            int kc = kt * 32 + (tid & 3) * 8;
            gl_lds16(g_ATTN + (long)gr0 * 1024 + kc, As + tid * 8);
            gl_lds16(g_ATTN + (long)gr1 * 1024 + kc, As + (tid + 256) * 8);
            const ushort* gb = g_WOB + (long)col0 * 1024 + kt * 32;
            int c0 = tid, c1 = tid + 256;
            gl_lds16(gb + (c0 >> 2) * 1024 + (c0 & 3) * 8, Bs + c0 * 8);
            gl_lds16(gb + (c1 >> 2) * 1024 + (c1 & 3) * 8, Bs + c1 * 8);
        }
        asm volatile("s_waitcnt vmcnt(0)" ::: "memory");
        __syncthreads();
        short8 af[4], bfr[4];
        #pragma unroll
        for (int mi = 0; mi < 4; mi++)
            af[mi] = *(const short8*)(As + (wm + mi * 16 + lq) * 32 + lg * 8);
        #pragma unroll
        for (int ni = 0; ni < 4; ni++)
            bfr[ni] = *(const short8*)(Bs + (wn + ni * 16 + lq) * 32 + lg * 8);
        #pragma unroll
        for (int mi = 0; mi < 4; mi++)
            #pragma unroll
            for (int ni = 0; ni < 4; ni++)
                acc[mi][ni] = MFMA16(af[mi], bfr[ni], acc[mi][ni]);
        __syncthreads();
    }
    #pragma unroll
    for (int mi = 0; mi < 4; mi++)
        #pragma unroll
        for (int r = 0; r < 4; r++) {
            int mm = row0 + wm + mi * 16 + lg * 4 + r;
            #pragma unroll
            for (int ni = 0; ni < 4; ni++) {
                int n = col0 + wn + ni * 16 + lq;
                out[(long)mm * 1024 + n] = acc[mi][ni][r] + bias[n];
            }
        }
}

extern "C" void kernel_launch(void* const* d_in, const int* in_sizes, int n_in,
                              void* d_out, int out_size, void* d_ws, size_t ws_size,
                              hipStream_t stream) {
    const float* x    = (const float*)d_in[0];
    const float* Wqkv = (const float*)d_in[1];
    const float* bqkv = (const float*)d_in[2];
    const float* Wout = (const float*)d_in[3];
    const float* bout = (const float*)d_in[4];
    float* out = (float*)d_out;
    (void)d_ws; (void)ws_size; (void)in_sizes; (void)n_in; (void)out_size;

    cvt_kernel<<<dim3(12288), dim3(256), 0, stream>>>(x, Wqkv, Wout);
    perm_kernel<<<dim3(3), dim3(1024), 0, stream>>>();
    qkv_gemm<<<dim3(64, 24), dim3(256), 0, stream>>>(bqkv);
    vtrans_kernel<<<dim3(1024), dim3(256), 0, stream>>>();
    attn_kernel<<<dim3(1024), dim3(256), 0, stream>>>();
    out_gemm<<<dim3(64, 8), dim3(256), 0, stream>>>(bout, out);
}

// Round 3
// 199.273 us; speedup vs baseline: 2.2053x; 1.3161x over previous
//
#include <hip/hip_runtime.h>
#include <math.h>

typedef short short8 __attribute__((ext_vector_type(8)));
typedef float fx4 __attribute__((ext_vector_type(4)));
typedef unsigned short ushort;
typedef unsigned int uint;
typedef uint uint2v __attribute__((ext_vector_type(2)));

#define MFMA16(a, b, c) __builtin_amdgcn_mfma_f32_16x16x32_bf16(a, b, c, 0, 0, 0)

// segments: len {2048,2048,4096}, dil {1,2,4}; q rows packed at [0,2048,4096];
// k/v rows (dilated) packed at [0,2048,3072], total 4096.
// Q pre-scaled by (1/8)*log2(e): softmax runs in log2 domain (v_exp_f32 = 2^x).
#define QSCALE 0.180336880f

__device__ __forceinline__ ushort f2bf(float f) {
    union { float f; uint u; } v; v.f = f;
    uint r = v.u + 0x7fffu + ((v.u >> 16) & 1u);
    return (ushort)(r >> 16);
}

__device__ __forceinline__ float exp2f_fast(float x) {
    float r; asm("v_exp_f32 %0, %1" : "=v"(r) : "v"(x)); return r;
}

__device__ __forceinline__ uint cvt_pk_bf16(float lo, float hi) {
    uint r; asm("v_cvt_pk_bf16_f32 %0, %1, %2" : "=v"(r) : "v"(lo), "v"(hi)); return r;
}

__device__ __forceinline__ void gl_lds16(const void* g, void* l) {
    __builtin_amdgcn_global_load_lds(
        (const __attribute__((address_space(1))) void*)g,
        (__attribute__((address_space(3))) void*)l, 16, 0, 0);
}

// ---- scratch (static device globals; fully rewritten every call) ----
__device__ ushort g_XB[8192 * 1024];      // x bf16 [s][k]
__device__ ushort g_WQB[3072 * 1024];     // Wqkv bf16 [n][k]
__device__ ushort g_WOB[1024 * 1024];     // Wout bf16 [n][k]
__device__ ushort g_QSEG[16 * 8192 * 64]; // [h][qrow][d], permuted, scaled by QSCALE
__device__ ushort g_KSEG[16 * 4096 * 64]; // [h][krow][d], permuted+dilated
__device__ ushort g_VSEG[16 * 4096 * 64]; // [h][krow][d]
__device__ ushort g_VT[16 * 64 * 4096];   // [h][d][krow]  (V transposed)
__device__ ushort g_ATTN[8192 * 1024];    // [qrow][h*64+d] bf16 (permuted row space)
__device__ int g_QROW[8192];              // s -> permuted q row (global)
__device__ int g_KVROW[8192];             // s -> dilated k/v row (global) or -1

// ---------------- convert f32 -> bf16 ----------------
__global__ __launch_bounds__(256) void cvt_kernel(const float* __restrict__ x,
                                                  const float* __restrict__ wq,
                                                  const float* __restrict__ wo) {
    int idx = blockIdx.x * 256 + threadIdx.x;
    const int NX = 8192 * 1024 / 4, NQ = 3072 * 1024 / 4, NO = 1024 * 1024 / 4;
    const float* s; ushort* d; int rel;
    if (idx < NX)            { s = x;  d = g_XB;  rel = idx; }
    else if (idx < NX + NQ)  { s = wq; d = g_WQB; rel = idx - NX; }
    else if (idx < NX + NQ + NO) { s = wo; d = g_WOB; rel = idx - NX - NQ; }
    else return;
    fx4 v = *(const fx4*)(s + (long)rel * 4);
    uint lo = f2bf(v[0]) | ((uint)f2bf(v[1]) << 16);
    uint hi = f2bf(v[2]) | ((uint)f2bf(v[3]) << 16);
    uint2v w; w[0] = lo; w[1] = hi;
    *(uint2v*)(d + (long)rel * 4) = w;
}

// ---------------- Hilbert perms + scatter metadata ----------------
__global__ __launch_bounds__(1024) void perm_kernel() {
    __shared__ int perm_lds[4096];
    __shared__ int inv_lds[4096];
    __shared__ int sc[1024];
    int seg = blockIdx.x;
    int L     = (seg == 2) ? 4096 : 2048;
    int dil   = (seg == 0) ? 1 : (seg == 1) ? 2 : 4;
    int pos   = (seg == 0) ? 0 : (seg == 1) ? 2048 : 4096;
    int kbase = (seg == 0) ? 0 : (seg == 1) ? 2048 : 3072;
    int tid = threadIdx.x;

    int lin[4]; int flg[4]; int cnt = 0;
    #pragma unroll
    for (int c = 0; c < 4; c++) {
        int d = tid * 4 + c;
        int x = 0, y = 0, t = d;
        for (int s = 1; s < 64; s <<= 1) {
            int rx = (t >> 1) & 1;
            int ry = (t ^ rx) & 1;
            if (ry == 0) {
                if (rx == 1) { x = s - 1 - x; y = s - 1 - y; }
                int tmp = x; x = y; y = tmp;
            }
            x += s * rx; y += s * ry; t >>= 2;
        }
        lin[c] = y * 64 + x;
        flg[c] = (lin[c] < L) ? 1 : 0;
        cnt += flg[c];
    }
    sc[tid] = cnt; __syncthreads();
    for (int off = 1; off < 1024; off <<= 1) {
        int v = sc[tid];
        int a = (tid >= off) ? sc[tid - off] : 0;
        __syncthreads();
        sc[tid] = v + a;
        __syncthreads();
    }
    int base = sc[tid] - cnt;
    #pragma unroll
    for (int c = 0; c < 4; c++) if (flg[c]) perm_lds[base++] = lin[c];
    __syncthreads();
    for (int i = tid; i < L; i += 1024) inv_lds[perm_lds[i]] = i;
    __syncthreads();
    for (int p = tid; p < L; p += 1024) {
        int i = inv_lds[p];
        int s = pos + p;
        g_QROW[s] = pos + i;
        g_KVROW[s] = ((i & (dil - 1)) == 0) ? (kbase + i / dil) : -1;
    }
}

// ---------------- QKV GEMM (BK=64, swizzled LDS): scatter epilogue ----------------
__global__ __launch_bounds__(256) void qkv_gemm(const float* __restrict__ bias) {
    __shared__ __align__(16) ushort As[128 * 64];
    __shared__ __align__(16) ushort Bs[128 * 64];
    int tid = threadIdx.x;
    int lane = tid & 63, wid = tid >> 6;
    int lq = lane & 15, lg = lane >> 4;
    int swz = lq & 7;
    int row0 = blockIdx.x * 128, col0 = blockIdx.y * 128;
    int wm = (wid >> 1) * 64, wn = (wid & 1) * 64;
    int crow = tid >> 3, cp = (tid & 7) ^ (crow & 7);
    fx4 acc[4][4] = {};
    for (int kt = 0; kt < 16; kt++) {
        const ushort* ga = g_XB + (long)row0 * 1024 + kt * 64;
        const ushort* gb = g_WQB + (long)col0 * 1024 + kt * 64;
        #pragma unroll
        for (int j = 0; j < 4; j++) {
            int c = tid + 256 * j;
            int r = crow + 32 * j;
            gl_lds16(ga + (long)r * 1024 + cp * 8, As + c * 8);
            gl_lds16(gb + (long)r * 1024 + cp * 8, Bs + c * 8);
        }
        asm volatile("s_waitcnt vmcnt(0)" ::: "memory");
        __syncthreads();
        short8 af[4][2], bfr[4][2];
        #pragma unroll
        for (int mi = 0; mi < 4; mi++)
            #pragma unroll
            for (int kk = 0; kk < 2; kk++)
                af[mi][kk] = *(const short8*)(As + (wm + mi * 16 + lq) * 64 + (((kk * 4 + lg) ^ swz) << 3));
        #pragma unroll
        for (int ni = 0; ni < 4; ni++)
            #pragma unroll
            for (int kk = 0; kk < 2; kk++)
                bfr[ni][kk] = *(const short8*)(Bs + (wn + ni * 16 + lq) * 64 + (((kk * 4 + lg) ^ swz) << 3));
        #pragma unroll
        for (int kk = 0; kk < 2; kk++)
            #pragma unroll
            for (int mi = 0; mi < 4; mi++)
                #pragma unroll
                for (int ni = 0; ni < 4; ni++)
                    acc[mi][ni] = MFMA16(af[mi][kk], bfr[ni][kk], acc[mi][ni]);
        __syncthreads();
    }
    int comp = col0 >> 10;  // uniform per block (128 | 1024)
    #pragma unroll
    for (int mi = 0; mi < 4; mi++) {
        int mbase = row0 + wm + mi * 16 + lg * 4;
        #pragma unroll
        for (int r = 0; r < 4; r++) {
            int m = mbase + r;
            int qr = g_QROW[m];
            int kr = g_KVROW[m];
            #pragma unroll
            for (int ni = 0; ni < 4; ni++) {
                int n = col0 + wn + ni * 16 + lq;
                float val = acc[mi][ni][r] + bias[n];
                int h = (n >> 6) & 15, dd = n & 63;
                if (comp == 0) {
                    g_QSEG[((long)h * 8192 + qr) * 64 + dd] = f2bf(val * QSCALE);
                } else if (kr >= 0) {
                    if (comp == 1) g_KSEG[((long)h * 4096 + kr) * 64 + dd] = f2bf(val);
                    else           g_VSEG[((long)h * 4096 + kr) * 64 + dd] = f2bf(val);
                }
            }
        }
    }
}

// ---------------- V transpose: [h][row][d] -> [h][d][row] ----------------
__global__ __launch_bounds__(256) void vtrans_kernel() {
    __shared__ __align__(16) ushort tile[64 * 80];
    int b = blockIdx.x; int h = b >> 6; int rt = b & 63;
    const ushort* src = g_VSEG + ((long)h * 4096 + rt * 64) * 64;
    int tid = threadIdx.x;
    for (int c = tid; c < 512; c += 256) {
        int row = c >> 3, ch = c & 7;
        *(short8*)&tile[row * 80 + ch * 8] = *(const short8*)(src + row * 64 + ch * 8);
    }
    __syncthreads();
    for (int c = tid; c < 512; c += 256) {
        int d = c >> 3, oc = c & 7;
        ushort tmp[8];
        #pragma unroll
        for (int e = 0; e < 8; e++) tmp[e] = tile[(oc * 8 + e) * 80 + d];
        *(short8*)&g_VT[((long)h * 64 + d) * 4096 + rt * 64 + oc * 8] = *(short8*)tmp;
    }
}

// ---------------- attention: flash, log2-softmax, ones-MFMA lsum ----------------
// Block = 4 waves x 32 q-rows. Grid remap: 256 long (seg0) blocks first.
__global__ __launch_bounds__(256, 3) void attn_kernel() {
    __shared__ __align__(16) ushort Kt[2][64 * 64];
    __shared__ __align__(16) ushort Vt[2][64 * 64];
    __shared__ __align__(16) ushort Plds[4][32 * 72];
    int bid = blockIdx.x;
    int seg, h, qblk;
    if (bid < 256)      { seg = 0; h = bid >> 4;         qblk = bid & 15; }
    else if (bid < 512) { seg = 1; h = (bid - 256) >> 4; qblk = (bid - 256) & 15; }
    else                { seg = 2; h = (bid - 512) >> 5; qblk = (bid - 512) & 31; }
    int qbase = (seg == 0) ? 0 : (seg == 1) ? 2048 : 4096;
    int kbase = (seg == 0) ? 0 : (seg == 1) ? 2048 : 3072;
    int nkt   = (seg == 0) ? 32 : 16;

    int tid = threadIdx.x;
    int lane = tid & 63, wid = tid >> 6;
    int lq = lane & 15, lg = lane >> 4;
    int swz = lq & 7;
    int qrow0 = qbase + qblk * 128 + wid * 32;

    const ushort* kseg = g_KSEG + (long)h * 4096 * 64;
    const ushort* vtb0 = g_VT + (long)h * 64 * 4096 + kbase;
    ushort* P = &Plds[wid][0];

    // staging: chunk c -> row c>>3, LDS piece c&7 <- src piece (c&7)^(row&7)
    int c0 = tid, c1 = tid + 256;
    int r0 = c0 >> 3, e0 = (c0 & 7) ^ (r0 & 7);
    int r1 = c1 >> 3, e1 = (c1 & 7) ^ (r1 & 7);
    const ushort* ka0 = kseg + (long)(kbase + r0) * 64 + e0 * 8;
    const ushort* ka1 = kseg + (long)(kbase + r1) * 64 + e1 * 8;
    const ushort* va0 = vtb0 + (long)r0 * 4096 + e0 * 8;
    const ushort* va1 = vtb0 + (long)r1 * 4096 + e1 * 8;

#define STAGE(b, kt_) do {                                                    \
        gl_lds16(ka0 + (long)(kt_) * 4096, &Kt[b][c0 * 8]);                   \
        gl_lds16(ka1 + (long)(kt_) * 4096, &Kt[b][c1 * 8]);                   \
        gl_lds16(va0 + (kt_) * 64, &Vt[b][c0 * 8]);                           \
        gl_lds16(va1 + (kt_) * 64, &Vt[b][c1 * 8]);                           \
    } while (0)

    // Q fragments (32 rows per wave), pre-scaled by QSCALE
    const ushort* qp = g_QSEG + ((long)h * 8192 + qrow0) * 64;
    short8 qf[2][2];
    #pragma unroll
    for (int qt = 0; qt < 2; qt++)
        #pragma unroll
        for (int hf = 0; hf < 2; hf++)
            qf[qt][hf] = *(const short8*)(qp + (qt * 16 + lq) * 64 + hf * 32 + lg * 8);

    short8 onesA;
    #pragma unroll
    for (int i = 0; i < 8; i++) onesA[i] = (short)0x3F80;

    STAGE(0, 0);
    asm volatile("s_waitcnt vmcnt(0)" ::: "memory");
    __syncthreads();

    fx4 accT[4][2] = {};
    fx4 lacc[2] = {};
    float m0 = -INFINITY, m1 = -INFINITY;

#define BODY(cur, kt_) do {                                                   \
        if ((kt_) + 1 < nkt) STAGE((cur) ^ 1, (kt_) + 1);                     \
        const ushort* Kc = Kt[cur];                                           \
        const ushort* Vc = Vt[cur];                                           \
        short8 kf[4][2];                                                      \
        _Pragma("unroll")                                                     \
        for (int t = 0; t < 4; t++)                                           \
            _Pragma("unroll")                                                 \
            for (int hf = 0; hf < 2; hf++)                                    \
                kf[t][hf] = *(const short8*)(Kc + (t * 16 + lq) * 64 + (((hf * 4 + lg) ^ swz) << 3)); \
        fx4 st[4][2];                                                         \
        __builtin_amdgcn_s_setprio(1);                                        \
        _Pragma("unroll")                                                     \
        for (int t = 0; t < 4; t++)                                           \
            _Pragma("unroll")                                                 \
            for (int qt = 0; qt < 2; qt++) {                                  \
                fx4 s = {};                                                   \
                s = MFMA16(kf[t][0], qf[qt][0], s);                           \
                s = MFMA16(kf[t][1], qf[qt][1], s);                           \
                st[t][qt] = s;                                                \
            }                                                                 \
        __builtin_amdgcn_s_setprio(0);                                        \
        float t0, t1;                                                         \
        {                                                                     \
            fx4 mx0 = st[0][0], mx1 = st[0][1];                               \
            _Pragma("unroll")                                                 \
            for (int t = 1; t < 4; t++) {                                     \
                mx0 = fx4{fmaxf(mx0[0], st[t][0][0]), fmaxf(mx0[1], st[t][0][1]), \
                          fmaxf(mx0[2], st[t][0][2]), fmaxf(mx0[3], st[t][0][3])}; \
                mx1 = fx4{fmaxf(mx1[0], st[t][1][0]), fmaxf(mx1[1], st[t][1][1]), \
                          fmaxf(mx1[2], st[t][1][2]), fmaxf(mx1[3], st[t][1][3])}; \
            }                                                                 \
            t0 = fmaxf(fmaxf(mx0[0], mx0[1]), fmaxf(mx0[2], mx0[3]));         \
            t1 = fmaxf(fmaxf(mx1[0], mx1[1]), fmaxf(mx1[2], mx1[3]));         \
            t0 = fmaxf(t0, __shfl_xor(t0, 16)); t0 = fmaxf(t0, __shfl_xor(t0, 32)); \
            t1 = fmaxf(t1, __shfl_xor(t1, 16)); t1 = fmaxf(t1, __shfl_xor(t1, 32)); \
        }                                                                     \
        if (__any((t0 > m0 + 8.f) || (t1 > m1 + 8.f))) {                      \
            float nm0 = fmaxf(m0, t0), nm1 = fmaxf(m1, t1);                   \
            float cr0 = exp2f_fast(m0 - nm0), cr1 = exp2f_fast(m1 - nm1);     \
            m0 = nm0; m1 = nm1;                                               \
            lacc[0] *= cr0; lacc[1] *= cr1;                                   \
            _Pragma("unroll")                                                 \
            for (int td = 0; td < 4; td++) {                                  \
                accT[td][0] *= cr0;                                           \
                accT[td][1] *= cr1;                                           \
            }                                                                 \
        }                                                                     \
        _Pragma("unroll")                                                     \
        for (int qt = 0; qt < 2; qt++) {                                      \
            float mm = qt ? m1 : m0;                                          \
            _Pragma("unroll")                                                 \
            for (int t = 0; t < 4; t++) {                                     \
                float p0 = exp2f_fast(st[t][qt][0] - mm);                     \
                float p1 = exp2f_fast(st[t][qt][1] - mm);                     \
                float p2 = exp2f_fast(st[t][qt][2] - mm);                     \
                float p3 = exp2f_fast(st[t][qt][3] - mm);                     \
                uint2v w;                                                     \
                w[0] = cvt_pk_bf16(p0, p1);                                   \
                w[1] = cvt_pk_bf16(p2, p3);                                   \
                *(uint2v*)(P + (qt * 16 + lq) * 72 + t * 16 + lg * 4) = w;    \
            }                                                                 \
        }                                                                     \
        short8 vf[4][2];                                                      \
        _Pragma("unroll")                                                     \
        for (int td = 0; td < 4; td++)                                        \
            _Pragma("unroll")                                                 \
            for (int hf = 0; hf < 2; hf++)                                    \
                vf[td][hf] = *(const short8*)(Vc + (td * 16 + lq) * 64 + (((hf * 4 + lg) ^ swz) << 3)); \
        __builtin_amdgcn_s_setprio(1);                                        \
        _Pragma("unroll")                                                     \
        for (int qt = 0; qt < 2; qt++) {                                      \
            short8 pb0 = *(const short8*)(P + (qt * 16 + lq) * 72 + lg * 8);  \
            short8 pb1 = *(const short8*)(P + (qt * 16 + lq) * 72 + 32 + lg * 8); \
            lacc[qt] = MFMA16(onesA, pb0, lacc[qt]);                          \
            lacc[qt] = MFMA16(onesA, pb1, lacc[qt]);                          \
            _Pragma("unroll")                                                 \
            for (int td = 0; td < 4; td++) {                                  \
                accT[td][qt] = MFMA16(vf[td][0], pb0, accT[td][qt]);          \
                accT[td][qt] = MFMA16(vf[td][1], pb1, accT[td][qt]);          \
            }                                                                 \
        }                                                                     \
        __builtin_amdgcn_s_setprio(0);                                        \
        asm volatile("s_waitcnt vmcnt(0)" ::: "memory");                      \
        __syncthreads();                                                      \
    } while (0)

    for (int kt = 0; kt < nkt; kt += 2) {
        BODY(0, kt);
        BODY(1, kt + 1);
    }
#undef BODY
#undef STAGE

    float ri0 = 1.0f / lacc[0][0];
    float ri1 = 1.0f / lacc[1][0];
    #pragma unroll
    for (int qt = 0; qt < 2; qt++) {
        float ri = qt ? ri1 : ri0;
        ushort* op = g_ATTN + (long)(qrow0 + qt * 16 + lq) * 1024 + h * 64;
        #pragma unroll
        for (int td = 0; td < 4; td++) {
            uint2v w;
            w[0] = cvt_pk_bf16(accT[td][qt][0] * ri, accT[td][qt][1] * ri);
            w[1] = cvt_pk_bf16(accT[td][qt][2] * ri, accT[td][qt][3] * ri);
            *(uint2v*)(op + td * 16 + lg * 4) = w;
        }
    }
}

// ---------------- output GEMM (BK=64, swizzled LDS, gathered A rows) ----------------
__global__ __launch_bounds__(256) void out_gemm(const float* __restrict__ bias,
                                                float* __restrict__ out) {
    __shared__ __align__(16) ushort As[128 * 64];
    __shared__ __align__(16) ushort Bs[128 * 64];
    int tid = threadIdx.x;
    int lane = tid & 63, wid = tid >> 6;
    int lq = lane & 15, lg = lane >> 4;
    int swz = lq & 7;
    int row0 = blockIdx.x * 128, col0 = blockIdx.y * 128;
    int wm = (wid >> 1) * 64, wn = (wid & 1) * 64;
    int crow = tid >> 3, cp = (tid & 7) ^ (crow & 7);
    int gr[4];
    #pragma unroll
    for (int j = 0; j < 4; j++) gr[j] = g_QROW[row0 + crow + 32 * j];
    fx4 acc[4][4] = {};
    for (int kt = 0; kt < 16; kt++) {
        const ushort* gb = g_WOB + (long)col0 * 1024 + kt * 64;
        #pragma unroll
        for (int j = 0; j < 4; j++) {
            int c = tid + 256 * j;
            gl_lds16(g_ATTN + (long)gr[j] * 1024 + kt * 64 + cp * 8, As + c * 8);
            gl_lds16(gb + (long)(crow + 32 * j) * 1024 + cp * 8, Bs + c * 8);
        }
        asm volatile("s_waitcnt vmcnt(0)" ::: "memory");
        __syncthreads();
        short8 af[4][2], bfr[4][2];
        #pragma unroll
        for (int mi = 0; mi < 4; mi++)
            #pragma unroll
            for (int kk = 0; kk < 2; kk++)
                af[mi][kk] = *(const short8*)(As + (wm + mi * 16 + lq) * 64 + (((kk * 4 + lg) ^ swz) << 3));
        #pragma unroll
        for (int ni = 0; ni < 4; ni++)
            #pragma unroll
            for (int kk = 0; kk < 2; kk++)
                bfr[ni][kk] = *(const short8*)(Bs + (wn + ni * 16 + lq) * 64 + (((kk * 4 + lg) ^ swz) << 3));
        #pragma unroll
        for (int kk = 0; kk < 2; kk++)
            #pragma unroll
            for (int mi = 0; mi < 4; mi++)
                #pragma unroll
                for (int ni = 0; ni < 4; ni++)
                    acc[mi][ni] = MFMA16(af[mi][kk], bfr[ni][kk], acc[mi][ni]);
        __syncthreads();
    }
    #pragma unroll
    for (int mi = 0; mi < 4; mi++)
        #pragma unroll
        for (int r = 0; r < 4; r++) {
            int mm = row0 + wm + mi * 16 + lg * 4 + r;
            #pragma unroll
            for (int ni = 0; ni < 4; ni++) {
                int n = col0 + wn + ni * 16 + lq;
                out[(long)mm * 1024 + n] = acc[mi][ni][r] + bias[n];
            }
        }
}

extern "C" void kernel_launch(void* const* d_in, const int* in_sizes, int n_in,
                              void* d_out, int out_size, void* d_ws, size_t ws_size,
                              hipStream_t stream) {
    const float* x    = (const float*)d_in[0];
    const float* Wqkv = (const float*)d_in[1];
    const float* bqkv = (const float*)d_in[2];
    const float* Wout = (const float*)d_in[3];
    const float* bout = (const float*)d_in[4];
    float* out = (float*)d_out;
    (void)d_ws; (void)ws_size; (void)in_sizes; (void)n_in; (void)out_size;

    cvt_kernel<<<dim3(12288), dim3(256), 0, stream>>>(x, Wqkv, Wout);
    perm_kernel<<<dim3(3), dim3(1024), 0, stream>>>();
    qkv_gemm<<<dim3(64, 24), dim3(256), 0, stream>>>(bqkv);
    vtrans_kernel<<<dim3(1024), dim3(256), 0, stream>>>();
    attn_kernel<<<dim3(1024), dim3(256), 0, stream>>>();
    out_gemm<<<dim3(64, 8), dim3(256), 0, stream>>>(bout, out);
}

// Round 4
// 193.676 us; speedup vs baseline: 2.2690x; 1.0289x over previous
//
#include <hip/hip_runtime.h>
#include <math.h>

typedef short short8 __attribute__((ext_vector_type(8)));
typedef float fx4 __attribute__((ext_vector_type(4)));
typedef unsigned short ushort;
typedef unsigned int uint;
typedef uint uint2v __attribute__((ext_vector_type(2)));

#define MFMA16(a, b, c) __builtin_amdgcn_mfma_f32_16x16x32_bf16(a, b, c, 0, 0, 0)

// segments: len {2048,2048,4096}, dil {1,2,4}; q rows packed at [0,2048,4096];
// k/v rows (dilated) packed at [0,2048,3072], total 4096.
// Q pre-scaled by (1/8)*log2(e): softmax runs in log2 domain (v_exp_f32 = 2^x).
#define QSCALE 0.180336880f

#define BAR() do { asm volatile("" ::: "memory"); __builtin_amdgcn_s_barrier(); asm volatile("" ::: "memory"); } while (0)
#define VMCNT(n) asm volatile("s_waitcnt vmcnt(" #n ")" ::: "memory")

__device__ __forceinline__ ushort f2bf(float f) {
    union { float f; uint u; } v; v.f = f;
    uint r = v.u + 0x7fffu + ((v.u >> 16) & 1u);
    return (ushort)(r >> 16);
}

__device__ __forceinline__ float exp2f_fast(float x) {
    float r; asm("v_exp_f32 %0, %1" : "=v"(r) : "v"(x)); return r;
}

__device__ __forceinline__ uint cvt_pk_bf16(float lo, float hi) {
    uint r; asm("v_cvt_pk_bf16_f32 %0, %1, %2" : "=v"(r) : "v"(lo), "v"(hi)); return r;
}

__device__ __forceinline__ void gl_lds16(const void* g, void* l) {
    __builtin_amdgcn_global_load_lds(
        (const __attribute__((address_space(1))) void*)g,
        (__attribute__((address_space(3))) void*)l, 16, 0, 0);
}

// ---- scratch (static device globals; fully rewritten every call) ----
__device__ ushort g_XB[8192 * 1024];      // x bf16 [s][k]
__device__ ushort g_WQB[3072 * 1024];     // Wqkv bf16 [n][k]
__device__ ushort g_WOB[1024 * 1024];     // Wout bf16 [n][k]
__device__ ushort g_QSEG[16 * 8192 * 64]; // [h][qrow][d], permuted, scaled by QSCALE
__device__ ushort g_KSEG[16 * 4096 * 64]; // [h][krow][d], permuted+dilated
__device__ ushort g_VSEG[16 * 4096 * 64]; // [h][krow][d]
__device__ ushort g_VT[16 * 64 * 4096];   // [h][d][krow]  (V transposed)
__device__ ushort g_ATTN[8192 * 1024];    // [qrow][h*64+d] bf16 (permuted row space)
__device__ int g_QROW[8192];              // s -> permuted q row (global)
__device__ int g_KVROW[8192];             // s -> dilated k/v row (global) or -1

// ---------------- convert f32 -> bf16 ----------------
__global__ __launch_bounds__(256) void cvt_kernel(const float* __restrict__ x,
                                                  const float* __restrict__ wq,
                                                  const float* __restrict__ wo) {
    int idx = blockIdx.x * 256 + threadIdx.x;
    const int NX = 8192 * 1024 / 4, NQ = 3072 * 1024 / 4, NO = 1024 * 1024 / 4;
    const float* s; ushort* d; int rel;
    if (idx < NX)            { s = x;  d = g_XB;  rel = idx; }
    else if (idx < NX + NQ)  { s = wq; d = g_WQB; rel = idx - NX; }
    else if (idx < NX + NQ + NO) { s = wo; d = g_WOB; rel = idx - NX - NQ; }
    else return;
    fx4 v = *(const fx4*)(s + (long)rel * 4);
    uint lo = f2bf(v[0]) | ((uint)f2bf(v[1]) << 16);
    uint hi = f2bf(v[2]) | ((uint)f2bf(v[3]) << 16);
    uint2v w; w[0] = lo; w[1] = hi;
    *(uint2v*)(d + (long)rel * 4) = w;
}

// ---------------- Hilbert perms + scatter metadata ----------------
__global__ __launch_bounds__(1024) void perm_kernel() {
    __shared__ int perm_lds[4096];
    __shared__ int inv_lds[4096];
    __shared__ int sc[1024];
    int seg = blockIdx.x;
    int L     = (seg == 2) ? 4096 : 2048;
    int dil   = (seg == 0) ? 1 : (seg == 1) ? 2 : 4;
    int pos   = (seg == 0) ? 0 : (seg == 1) ? 2048 : 4096;
    int kbase = (seg == 0) ? 0 : (seg == 1) ? 2048 : 3072;
    int tid = threadIdx.x;

    int lin[4]; int flg[4]; int cnt = 0;
    #pragma unroll
    for (int c = 0; c < 4; c++) {
        int d = tid * 4 + c;
        int x = 0, y = 0, t = d;
        for (int s = 1; s < 64; s <<= 1) {
            int rx = (t >> 1) & 1;
            int ry = (t ^ rx) & 1;
            if (ry == 0) {
                if (rx == 1) { x = s - 1 - x; y = s - 1 - y; }
                int tmp = x; x = y; y = tmp;
            }
            x += s * rx; y += s * ry; t >>= 2;
        }
        lin[c] = y * 64 + x;
        flg[c] = (lin[c] < L) ? 1 : 0;
        cnt += flg[c];
    }
    sc[tid] = cnt; __syncthreads();
    for (int off = 1; off < 1024; off <<= 1) {
        int v = sc[tid];
        int a = (tid >= off) ? sc[tid - off] : 0;
        __syncthreads();
        sc[tid] = v + a;
        __syncthreads();
    }
    int base = sc[tid] - cnt;
    #pragma unroll
    for (int c = 0; c < 4; c++) if (flg[c]) perm_lds[base++] = lin[c];
    __syncthreads();
    for (int i = tid; i < L; i += 1024) inv_lds[perm_lds[i]] = i;
    __syncthreads();
    for (int p = tid; p < L; p += 1024) {
        int i = inv_lds[p];
        int s = pos + p;
        g_QROW[s] = pos + i;
        g_KVROW[s] = ((i & (dil - 1)) == 0) ? (kbase + i / dil) : -1;
    }
}

// =====================================================================
// Pipelined GEMM core: BM=128, BN=256, BK=64, 512 threads (8 waves, 2Mx4N).
// Per-wave 64 rows x (2x32) split cols so B-half0 consumed in P1, half1 in P2.
// Counted vmcnt: P1-end vmcnt(4) (guarantees B1 of current tile),
// P2-end vmcnt(2) (guarantees A,B0 of next tile). Raw s_barrier, no drains.
// K = 1024 -> 16 K-tiles, last tile peeled.
// =====================================================================

// ---------------- QKV GEMM: out[s][n] = x@Wqkv^T + b, scatter epilogue ----------------
__global__ __launch_bounds__(512, 2) void qkv_gemm8(const float* __restrict__ bias) {
    __shared__ __align__(16) ushort AT[2][128 * 64];
    __shared__ __align__(16) ushort BT[2][256 * 64];
    const int tid = threadIdx.x;
    const int lane = tid & 63;
    const int wid = tid >> 6;
    const int lq = lane & 15, lg = lane >> 4;
    const int swz = lq & 7;
    const int wr = wid >> 2, wc = wid & 3;
    const int row0 = blockIdx.x * 128, col0 = blockIdx.y * 256;

    // staging source pointers (chunk c -> row c>>3, src piece (c&7)^(row&7))
    int ca0 = tid, ca1 = tid + 512;
    int ra0 = ca0 >> 3, pa0 = (ca0 & 7) ^ (ra0 & 7);
    int ra1 = ca1 >> 3, pa1 = (ca1 & 7) ^ (ra1 & 7);
    const ushort* sA0 = g_XB + (long)(row0 + ra0) * 1024 + pa0 * 8;
    const ushort* sA1 = g_XB + (long)(row0 + ra1) * 1024 + pa1 * 8;
    const ushort* sB[4];
    #pragma unroll
    for (int j = 0; j < 4; j++) {
        int c = tid + 512 * j;
        int r = c >> 3, p = (c & 7) ^ (r & 7);
        sB[j] = g_WQB + (long)(col0 + r) * 1024 + p * 8;
    }

#define STG_A(b, kt_) do { gl_lds16(sA0 + (kt_) * 64, &AT[b][ca0 * 8]);      \
                           gl_lds16(sA1 + (kt_) * 64, &AT[b][ca1 * 8]); } while (0)
#define STG_B0(b, kt_) do { gl_lds16(sB[0] + (kt_) * 64, &BT[b][tid * 8]);   \
                            gl_lds16(sB[1] + (kt_) * 64, &BT[b][(tid + 512) * 8]); } while (0)
#define STG_B1(b, kt_) do { gl_lds16(sB[2] + (kt_) * 64, &BT[b][(tid + 1024) * 8]); \
                            gl_lds16(sB[3] + (kt_) * 64, &BT[b][(tid + 1536) * 8]); } while (0)

    fx4 acc[4][4] = {};
    short8 af[4][2], bf0[2][2], bf1[2][2];

    // prologue: tile 0, order A, B0, B1
    STG_A(0, 0); STG_B0(0, 0); STG_B1(0, 0);
    VMCNT(2);
    BAR();

#define LD_A(cur)                                                             \
    _Pragma("unroll")                                                         \
    for (int mi = 0; mi < 4; mi++)                                            \
        _Pragma("unroll")                                                     \
        for (int kk = 0; kk < 2; kk++)                                        \
            af[mi][kk] = *(const short8*)(&AT[cur][(wr * 64 + mi * 16 + lq) * 64 + (((kk * 4 + lg) ^ swz) << 3)]);
#define LD_B0(cur)                                                            \
    _Pragma("unroll")                                                         \
    for (int nj = 0; nj < 2; nj++)                                            \
        _Pragma("unroll")                                                     \
        for (int kk = 0; kk < 2; kk++)                                        \
            bf0[nj][kk] = *(const short8*)(&BT[cur][(wc * 32 + nj * 16 + lq) * 64 + (((kk * 4 + lg) ^ swz) << 3)]);
#define LD_B1(cur)                                                            \
    _Pragma("unroll")                                                         \
    for (int nj = 0; nj < 2; nj++)                                            \
        _Pragma("unroll")                                                     \
        for (int kk = 0; kk < 2; kk++)                                        \
            bf1[nj][kk] = *(const short8*)(&BT[cur][(128 + wc * 32 + nj * 16 + lq) * 64 + (((kk * 4 + lg) ^ swz) << 3)]);
#define MM0()                                                                 \
    __builtin_amdgcn_s_setprio(1);                                            \
    _Pragma("unroll")                                                         \
    for (int kk = 0; kk < 2; kk++)                                            \
        _Pragma("unroll")                                                     \
        for (int mi = 0; mi < 4; mi++)                                        \
            _Pragma("unroll")                                                 \
            for (int nj = 0; nj < 2; nj++)                                    \
                acc[mi][nj] = MFMA16(af[mi][kk], bf0[nj][kk], acc[mi][nj]);    \
    __builtin_amdgcn_s_setprio(0);
#define MM1()                                                                 \
    __builtin_amdgcn_s_setprio(1);                                            \
    _Pragma("unroll")                                                         \
    for (int kk = 0; kk < 2; kk++)                                            \
        _Pragma("unroll")                                                     \
        for (int mi = 0; mi < 4; mi++)                                        \
            _Pragma("unroll")                                                 \
            for (int nj = 0; nj < 2; nj++)                                    \
                acc[mi][nj + 2] = MFMA16(af[mi][kk], bf1[nj][kk], acc[mi][nj + 2]); \
    __builtin_amdgcn_s_setprio(0);

    for (int kt = 0; kt < 15; kt++) {
        int cur = kt & 1, nxt = cur ^ 1;
        // P1
        LD_A(cur); LD_B0(cur);
        STG_A(nxt, kt + 1); STG_B0(nxt, kt + 1);
        MM0();
        VMCNT(4);
        BAR();
        // P2
        LD_B1(cur);
        STG_B1(nxt, kt + 1);
        MM1();
        VMCNT(2);
        BAR();
    }
    // peeled tile 15 (cur = 1)
    LD_A(1); LD_B0(1);
    MM0();
    VMCNT(0);
    BAR();
    LD_B1(1);
    MM1();

#undef STG_A
#undef STG_B0
#undef STG_B1

    // scatter epilogue
    int comp = col0 >> 10;  // uniform per block (256 | 1024)
    #pragma unroll
    for (int mi = 0; mi < 4; mi++) {
        int mbase = row0 + wr * 64 + mi * 16 + lg * 4;
        #pragma unroll
        for (int r = 0; r < 4; r++) {
            int m = mbase + r;
            int qr = g_QROW[m];
            int kr = g_KVROW[m];
            #pragma unroll
            for (int nj = 0; nj < 4; nj++) {
                int n = col0 + (nj >> 1) * 128 + wc * 32 + (nj & 1) * 16 + lq;
                float val = acc[mi][nj][r] + bias[n];
                int h = (n >> 6) & 15, dd = n & 63;
                if (comp == 0) {
                    g_QSEG[((long)h * 8192 + qr) * 64 + dd] = f2bf(val * QSCALE);
                } else if (kr >= 0) {
                    if (comp == 1) g_KSEG[((long)h * 4096 + kr) * 64 + dd] = f2bf(val);
                    else           g_VSEG[((long)h * 4096 + kr) * 64 + dd] = f2bf(val);
                }
            }
        }
    }
}

// ---------------- output GEMM: out[s][e] = attn[qrow[s]] @ Wout^T + b ----------------
__global__ __launch_bounds__(512, 2) void out_gemm8(const float* __restrict__ bias,
                                                    float* __restrict__ out) {
    __shared__ __align__(16) ushort AT[2][128 * 64];
    __shared__ __align__(16) ushort BT[2][256 * 64];
    const int tid = threadIdx.x;
    const int lane = tid & 63;
    const int wid = tid >> 6;
    const int lq = lane & 15, lg = lane >> 4;
    const int swz = lq & 7;
    const int wr = wid >> 2, wc = wid & 3;
    const int row0 = blockIdx.x * 128, col0 = blockIdx.y * 256;

    int ca0 = tid, ca1 = tid + 512;
    int ra0 = ca0 >> 3, pa0 = (ca0 & 7) ^ (ra0 & 7);
    int ra1 = ca1 >> 3, pa1 = (ca1 & 7) ^ (ra1 & 7);
    const ushort* sA0 = g_ATTN + (long)g_QROW[row0 + ra0] * 1024 + pa0 * 8;
    const ushort* sA1 = g_ATTN + (long)g_QROW[row0 + ra1] * 1024 + pa1 * 8;
    const ushort* sB[4];
    #pragma unroll
    for (int j = 0; j < 4; j++) {
        int c = tid + 512 * j;
        int r = c >> 3, p = (c & 7) ^ (r & 7);
        sB[j] = g_WOB + (long)(col0 + r) * 1024 + p * 8;
    }

#define STG_A(b, kt_) do { gl_lds16(sA0 + (kt_) * 64, &AT[b][ca0 * 8]);      \
                           gl_lds16(sA1 + (kt_) * 64, &AT[b][ca1 * 8]); } while (0)
#define STG_B0(b, kt_) do { gl_lds16(sB[0] + (kt_) * 64, &BT[b][tid * 8]);   \
                            gl_lds16(sB[1] + (kt_) * 64, &BT[b][(tid + 512) * 8]); } while (0)
#define STG_B1(b, kt_) do { gl_lds16(sB[2] + (kt_) * 64, &BT[b][(tid + 1024) * 8]); \
                            gl_lds16(sB[3] + (kt_) * 64, &BT[b][(tid + 1536) * 8]); } while (0)

    fx4 acc[4][4] = {};
    short8 af[4][2], bf0[2][2], bf1[2][2];

    STG_A(0, 0); STG_B0(0, 0); STG_B1(0, 0);
    VMCNT(2);
    BAR();

    for (int kt = 0; kt < 15; kt++) {
        int cur = kt & 1, nxt = cur ^ 1;
        LD_A(cur); LD_B0(cur);
        STG_A(nxt, kt + 1); STG_B0(nxt, kt + 1);
        MM0();
        VMCNT(4);
        BAR();
        LD_B1(cur);
        STG_B1(nxt, kt + 1);
        MM1();
        VMCNT(2);
        BAR();
    }
    LD_A(1); LD_B0(1);
    MM0();
    VMCNT(0);
    BAR();
    LD_B1(1);
    MM1();

#undef STG_A
#undef STG_B0
#undef STG_B1

    #pragma unroll
    for (int mi = 0; mi < 4; mi++)
        #pragma unroll
        for (int r = 0; r < 4; r++) {
            int mm = row0 + wr * 64 + mi * 16 + lg * 4 + r;
            #pragma unroll
            for (int nj = 0; nj < 4; nj++) {
                int n = col0 + (nj >> 1) * 128 + wc * 32 + (nj & 1) * 16 + lq;
                out[(long)mm * 1024 + n] = acc[mi][nj][r] + bias[n];
            }
        }
}

// ---------------- V transpose: [h][row][d] -> [h][d][row] ----------------
__global__ __launch_bounds__(256) void vtrans_kernel() {
    __shared__ __align__(16) ushort tile[64 * 80];
    int b = blockIdx.x; int h = b >> 6; int rt = b & 63;
    const ushort* src = g_VSEG + ((long)h * 4096 + rt * 64) * 64;
    int tid = threadIdx.x;
    for (int c = tid; c < 512; c += 256) {
        int row = c >> 3, ch = c & 7;
        *(short8*)&tile[row * 80 + ch * 8] = *(const short8*)(src + row * 64 + ch * 8);
    }
    __syncthreads();
    for (int c = tid; c < 512; c += 256) {
        int d = c >> 3, oc = c & 7;
        ushort tmp[8];
        #pragma unroll
        for (int e = 0; e < 8; e++) tmp[e] = tile[(oc * 8 + e) * 80 + d];
        *(short8*)&g_VT[((long)h * 64 + d) * 4096 + rt * 64 + oc * 8] = *(short8*)tmp;
    }
}

// ---------------- attention: flash, log2-softmax, ones-MFMA lsum ----------------
__global__ __launch_bounds__(256, 3) void attn_kernel() {
    __shared__ __align__(16) ushort Kt[2][64 * 64];
    __shared__ __align__(16) ushort Vt[2][64 * 64];
    __shared__ __align__(16) ushort Plds[4][32 * 72];
    int bid = blockIdx.x;
    int seg, h, qblk;
    if (bid < 256)      { seg = 0; h = bid >> 4;         qblk = bid & 15; }
    else if (bid < 512) { seg = 1; h = (bid - 256) >> 4; qblk = (bid - 256) & 15; }
    else                { seg = 2; h = (bid - 512) >> 5; qblk = (bid - 512) & 31; }
    int qbase = (seg == 0) ? 0 : (seg == 1) ? 2048 : 4096;
    int kbase = (seg == 0) ? 0 : (seg == 1) ? 2048 : 3072;
    int nkt   = (seg == 0) ? 32 : 16;

    int tid = threadIdx.x;
    int lane = tid & 63, wid = tid >> 6;
    int lq = lane & 15, lg = lane >> 4;
    int swz = lq & 7;
    int qrow0 = qbase + qblk * 128 + wid * 32;

    const ushort* kseg = g_KSEG + (long)h * 4096 * 64;
    const ushort* vtb0 = g_VT + (long)h * 64 * 4096 + kbase;
    ushort* P = &Plds[wid][0];

    int c0 = tid, c1 = tid + 256;
    int r0 = c0 >> 3, e0 = (c0 & 7) ^ (r0 & 7);
    int r1 = c1 >> 3, e1 = (c1 & 7) ^ (r1 & 7);
    const ushort* ka0 = kseg + (long)(kbase + r0) * 64 + e0 * 8;
    const ushort* ka1 = kseg + (long)(kbase + r1) * 64 + e1 * 8;
    const ushort* va0 = vtb0 + (long)r0 * 4096 + e0 * 8;
    const ushort* va1 = vtb0 + (long)r1 * 4096 + e1 * 8;

#define STAGE(b, kt_) do {                                                    \
        gl_lds16(ka0 + (long)(kt_) * 4096, &Kt[b][c0 * 8]);                   \
        gl_lds16(ka1 + (long)(kt_) * 4096, &Kt[b][c1 * 8]);                   \
        gl_lds16(va0 + (kt_) * 64, &Vt[b][c0 * 8]);                           \
        gl_lds16(va1 + (kt_) * 64, &Vt[b][c1 * 8]);                           \
    } while (0)

    const ushort* qp = g_QSEG + ((long)h * 8192 + qrow0) * 64;
    short8 qf[2][2];
    #pragma unroll
    for (int qt = 0; qt < 2; qt++)
        #pragma unroll
        for (int hf = 0; hf < 2; hf++)
            qf[qt][hf] = *(const short8*)(qp + (qt * 16 + lq) * 64 + hf * 32 + lg * 8);

    short8 onesA;
    #pragma unroll
    for (int i = 0; i < 8; i++) onesA[i] = (short)0x3F80;

    STAGE(0, 0);
    asm volatile("s_waitcnt vmcnt(0)" ::: "memory");
    __syncthreads();

    fx4 accT[4][2] = {};
    fx4 lacc[2] = {};
    float m0 = -INFINITY, m1 = -INFINITY;

#define BODY(cur, kt_) do {                                                   \
        if ((kt_) + 1 < nkt) STAGE((cur) ^ 1, (kt_) + 1);                     \
        const ushort* Kc = Kt[cur];                                           \
        const ushort* Vc = Vt[cur];                                           \
        short8 kf[4][2];                                                      \
        _Pragma("unroll")                                                     \
        for (int t = 0; t < 4; t++)                                           \
            _Pragma("unroll")                                                 \
            for (int hf = 0; hf < 2; hf++)                                    \
                kf[t][hf] = *(const short8*)(Kc + (t * 16 + lq) * 64 + (((hf * 4 + lg) ^ swz) << 3)); \
        fx4 st[4][2];                                                         \
        __builtin_amdgcn_s_setprio(1);                                        \
        _Pragma("unroll")                                                     \
        for (int t = 0; t < 4; t++)                                           \
            _Pragma("unroll")                                                 \
            for (int qt = 0; qt < 2; qt++) {                                  \
                fx4 s = {};                                                   \
                s = MFMA16(kf[t][0], qf[qt][0], s);                           \
                s = MFMA16(kf[t][1], qf[qt][1], s);                           \
                st[t][qt] = s;                                                \
            }                                                                 \
        __builtin_amdgcn_s_setprio(0);                                        \
        float t0, t1;                                                         \
        {                                                                     \
            fx4 mx0 = st[0][0], mx1 = st[0][1];                               \
            _Pragma("unroll")                                                 \
            for (int t = 1; t < 4; t++) {                                     \
                mx0 = fx4{fmaxf(mx0[0], st[t][0][0]), fmaxf(mx0[1], st[t][0][1]), \
                          fmaxf(mx0[2], st[t][0][2]), fmaxf(mx0[3], st[t][0][3])}; \
                mx1 = fx4{fmaxf(mx1[0], st[t][1][0]), fmaxf(mx1[1], st[t][1][1]), \
                          fmaxf(mx1[2], st[t][1][2]), fmaxf(mx1[3], st[t][1][3])}; \
            }                                                                 \
            t0 = fmaxf(fmaxf(mx0[0], mx0[1]), fmaxf(mx0[2], mx0[3]));         \
            t1 = fmaxf(fmaxf(mx1[0], mx1[1]), fmaxf(mx1[2], mx1[3]));         \
            t0 = fmaxf(t0, __shfl_xor(t0, 16)); t0 = fmaxf(t0, __shfl_xor(t0, 32)); \
            t1 = fmaxf(t1, __shfl_xor(t1, 16)); t1 = fmaxf(t1, __shfl_xor(t1, 32)); \
        }                                                                     \
        if (__any((t0 > m0 + 8.f) || (t1 > m1 + 8.f))) {                      \
            float nm0 = fmaxf(m0, t0), nm1 = fmaxf(m1, t1);                   \
            float cr0 = exp2f_fast(m0 - nm0), cr1 = exp2f_fast(m1 - nm1);     \
            m0 = nm0; m1 = nm1;                                               \
            lacc[0] *= cr0; lacc[1] *= cr1;                                   \
            _Pragma("unroll")                                                 \
            for (int td = 0; td < 4; td++) {                                  \
                accT[td][0] *= cr0;                                           \
                accT[td][1] *= cr1;                                           \
            }                                                                 \
        }                                                                     \
        _Pragma("unroll")                                                     \
        for (int qt = 0; qt < 2; qt++) {                                      \
            float mm = qt ? m1 : m0;                                          \
            _Pragma("unroll")                                                 \
            for (int t = 0; t < 4; t++) {                                     \
                float p0 = exp2f_fast(st[t][qt][0] - mm);                     \
                float p1 = exp2f_fast(st[t][qt][1] - mm);                     \
                float p2 = exp2f_fast(st[t][qt][2] - mm);                     \
                float p3 = exp2f_fast(st[t][qt][3] - mm);                     \
                uint2v w;                                                     \
                w[0] = cvt_pk_bf16(p0, p1);                                   \
                w[1] = cvt_pk_bf16(p2, p3);                                   \
                *(uint2v*)(P + (qt * 16 + lq) * 72 + t * 16 + lg * 4) = w;    \
            }                                                                 \
        }                                                                     \
        short8 vf[4][2];                                                      \
        _Pragma("unroll")                                                     \
        for (int td = 0; td < 4; td++)                                        \
            _Pragma("unroll")                                                 \
            for (int hf = 0; hf < 2; hf++)                                    \
                vf[td][hf] = *(const short8*)(Vc + (td * 16 + lq) * 64 + (((hf * 4 + lg) ^ swz) << 3)); \
        __builtin_amdgcn_s_setprio(1);                                        \
        _Pragma("unroll")                                                     \
        for (int qt = 0; qt < 2; qt++) {                                      \
            short8 pb0 = *(const short8*)(P + (qt * 16 + lq) * 72 + lg * 8);  \
            short8 pb1 = *(const short8*)(P + (qt * 16 + lq) * 72 + 32 + lg * 8); \
            lacc[qt] = MFMA16(onesA, pb0, lacc[qt]);                          \
            lacc[qt] = MFMA16(onesA, pb1, lacc[qt]);                          \
            _Pragma("unroll")                                                 \
            for (int td = 0; td < 4; td++) {                                  \
                accT[td][qt] = MFMA16(vf[td][0], pb0, accT[td][qt]);          \
                accT[td][qt] = MFMA16(vf[td][1], pb1, accT[td][qt]);          \
            }                                                                 \
        }                                                                     \
        __builtin_amdgcn_s_setprio(0);                                        \
        asm volatile("s_waitcnt vmcnt(0)" ::: "memory");                      \
        __syncthreads();                                                      \
    } while (0)

    for (int kt = 0; kt < nkt; kt += 2) {
        BODY(0, kt);
        BODY(1, kt + 1);
    }
#undef BODY
#undef STAGE

    float ri0 = 1.0f / lacc[0][0];
    float ri1 = 1.0f / lacc[1][0];
    #pragma unroll
    for (int qt = 0; qt < 2; qt++) {
        float ri = qt ? ri1 : ri0;
        ushort* op = g_ATTN + (long)(qrow0 + qt * 16 + lq) * 1024 + h * 64;
        #pragma unroll
        for (int td = 0; td < 4; td++) {
            uint2v w;
            w[0] = cvt_pk_bf16(accT[td][qt][0] * ri, accT[td][qt][1] * ri);
            w[1] = cvt_pk_bf16(accT[td][qt][2] * ri, accT[td][qt][3] * ri);
            *(uint2v*)(op + td * 16 + lg * 4) = w;
        }
    }
}

extern "C" void kernel_launch(void* const* d_in, const int* in_sizes, int n_in,
                              void* d_out, int out_size, void* d_ws, size_t ws_size,
                              hipStream_t stream) {
    const float* x    = (const float*)d_in[0];
    const float* Wqkv = (const float*)d_in[1];
    const float* bqkv = (const float*)d_in[2];
    const float* Wout = (const float*)d_in[3];
    const float* bout = (const float*)d_in[4];
    float* out = (float*)d_out;
    (void)d_ws; (void)ws_size; (void)in_sizes; (void)n_in; (void)out_size;

    cvt_kernel<<<dim3(12288), dim3(256), 0, stream>>>(x, Wqkv, Wout);
    perm_kernel<<<dim3(3), dim3(1024), 0, stream>>>();
    qkv_gemm8<<<dim3(64, 12), dim3(512), 0, stream>>>(bqkv);
    vtrans_kernel<<<dim3(1024), dim3(256), 0, stream>>>();
    attn_kernel<<<dim3(1024), dim3(256), 0, stream>>>();
    out_gemm8<<<dim3(64, 4), dim3(512), 0, stream>>>(bout, out);
}